// Round 1
// baseline (180.128 us; speedup 1.0000x reference)
//
#include <hip/hip_runtime.h>

#define BDIM 256
constexpr int Bn = 16, Cn = 4, Hn = 512, Wn = 512;
constexpr int BC = Bn * Cn;                    // 64 slices
constexpr float NTOT = 16777216.0f;            // B*C*H*W
constexpr int GPS = Hn * Wn / 4;               // int4/float4 groups per slice = 65536
constexpr int BPS = 32;                        // blocks per slice
constexpr int GPB = GPS / BPS;                 // 2048 groups per block
constexpr int ITERS = GPB / BDIM;              // 8 groups per thread
constexpr float SMOOTHF = 0.0001f;

__device__ __forceinline__ float wave_reduce(float v) {
#pragma unroll
    for (int off = 32; off > 0; off >>= 1) v += __shfl_down(v, off);
    return v;
}

__global__ __launch_bounds__(BDIM) void seg_main(const float4* __restrict__ cmap,
                                                 const int4* __restrict__ gt,
                                                 float* __restrict__ acc) {
    const int slice = blockIdx.x / BPS;
    const int bis   = blockIdx.x % BPS;
    const int* gts  = (const int*)gt;

    float ce = 0.f, ed = 0.f, inter = 0.f, isum = 0.f, jsum = 0.f;

    for (int it = 0; it < ITERS; ++it) {
        const int g   = bis * GPB + it * BDIM + threadIdx.x;  // group within slice
        const int idx = slice * GPS + g;
        const float4 x4 = cmap[idx];
        const int4   c4 = gt[idx];
        const int row  = g >> 7;    // 128 groups per row
        const int colg = g & 127;

        int4 u4 = make_int4(0, 0, 0, 0);
        int4 d4 = make_int4(0, 0, 0, 0);
        if (row > 0)      u4 = gt[idx - 128];
        if (row < Hn - 1) d4 = gt[idx + 128];
        const int lm = (colg > 0)   ? gts[idx * 4 - 1] : 0;
        const int rp = (colg < 127) ? gts[idx * 4 + 4] : 0;

        const float xs[4] = {x4.x, x4.y, x4.z, x4.w};
        const int   cs[4] = {c4.x, c4.y, c4.z, c4.w};
        const int   us[4] = {u4.x, u4.y, u4.z, u4.w};
        const int   dn[4] = {d4.x, d4.y, d4.z, d4.w};
        const int   ls[4] = {lm, c4.x, c4.y, c4.z};
        const int   rs[4] = {c4.y, c4.z, c4.w, rp};

#pragma unroll
        for (int i = 0; i < 4; ++i) {
            const float x = xs[i];
            const float y = (float)cs[i];
            const float t = __expf(-fabsf(x));           // exp(-|x|) in (0,1]
            const float sp = fmaxf(x, 0.f) + __logf(1.f + t);   // softplus(x)
            const float pred = (x >= 0.f ? 1.f : t) / (1.f + t); // sigmoid(x)

            ce += sp - x * y;

            const int mx = max(max(max(max(cs[i], us[i]), dn[i]), ls[i]), rs[i]);
            const int mn = min(min(min(min(cs[i], us[i]), dn[i]), ls[i]), rs[i]);
            if (mx != 0 && mn == 0) ed += fminf(sp, 100.f);  // -max(log1p(-pred),-100)

            inter += y * pred;
            isum  += y;
            jsum  += pred;
        }
    }

    // Block reduction of 5 partials
    __shared__ float sm[5][4];
    const int wave = threadIdx.x >> 6;
    const int lane = threadIdx.x & 63;
    ce    = wave_reduce(ce);
    ed    = wave_reduce(ed);
    inter = wave_reduce(inter);
    isum  = wave_reduce(isum);
    jsum  = wave_reduce(jsum);
    if (lane == 0) {
        sm[0][wave] = ce; sm[1][wave] = ed; sm[2][wave] = inter;
        sm[3][wave] = isum; sm[4][wave] = jsum;
    }
    __syncthreads();
    if (threadIdx.x == 0) {
        float tin = sm[2][0] + sm[2][1] + sm[2][2] + sm[2][3];
        float tis = sm[3][0] + sm[3][1] + sm[3][2] + sm[3][3];
        float tjs = sm[4][0] + sm[4][1] + sm[4][2] + sm[4][3];
        atomicAdd(&acc[slice * 3 + 0], tin);
        atomicAdd(&acc[slice * 3 + 1], tis);
        atomicAdd(&acc[slice * 3 + 2], tjs);
        float tce = sm[0][0] + sm[0][1] + sm[0][2] + sm[0][3];
        float ted = sm[1][0] + sm[1][1] + sm[1][2] + sm[1][3];
        atomicAdd(&acc[BC * 3 + 0], tce);
        atomicAdd(&acc[BC * 3 + 1], ted);
    }
}

__global__ void seg_finish(const float* __restrict__ acc, float* __restrict__ out) {
    const int t = threadIdx.x;  // 64 threads, one per (b,c) slice
    const float inter = acc[t * 3 + 0];
    const float is    = acc[t * 3 + 1];
    const float js    = acc[t * 3 + 2];
    const float score = (2.f * inter + SMOOTHF) / (is + js + SMOOTHF);
    float v = (1.f - score) * (1.f / (float)Bn);  // mean over batch, summed over C below
    v = wave_reduce(v);
    if (t == 0) {
        const float ce = acc[BC * 3 + 0] * (1.f / NTOT);
        const float ed = acc[BC * 3 + 1] * (1.f / NTOT);
        out[0] = ce + ed + v;
    }
}

extern "C" void kernel_launch(void* const* d_in, const int* in_sizes, int n_in,
                              void* d_out, int out_size, void* d_ws, size_t ws_size,
                              hipStream_t stream) {
    const float4* cmap = (const float4*)d_in[0];
    const int4*   gt   = (const int4*)d_in[1];
    float* acc = (float*)d_ws;
    hipMemsetAsync(acc, 0, (BC * 3 + 2) * sizeof(float), stream);
    seg_main<<<BC * BPS, BDIM, 0, stream>>>(cmap, gt, acc);
    seg_finish<<<1, 64, 0, stream>>>(acc, (float*)d_out);
}

// Round 2
// 148.304 us; speedup vs baseline: 1.2146x; 1.2146x over previous
//
#include <hip/hip_runtime.h>

#define BDIM 256
constexpr int Bn = 16, Cn = 4, Hn = 512, Wn = 512;
constexpr int BC = Bn * Cn;                  // 64 slices
constexpr float NTOT = 16777216.0f;          // B*C*H*W
constexpr int GPS = Hn * Wn / 4;             // int4/float4 groups per slice = 65536
constexpr int BPS = 32;                      // blocks per slice
constexpr int GPB = GPS / BPS;               // 2048 groups per block (16 rows)
constexpr int ITERS = GPB / BDIM;            // 8 groups per thread
constexpr int NBLK = BC * BPS;               // 2048 blocks
constexpr float SMOOTHF = 0.0001f;

__device__ __forceinline__ float wave_reduce(float v) {
#pragma unroll
    for (int off = 32; off > 0; off >>= 1) v += __shfl_down(v, off);
    return v;
}

// TOP: block holds row 0 of its slice (bis==0)   -> u-guard at it==0, tid<128
// BOT: block holds row 511 of its slice (bis==31)-> d-guard at it==7, tid>=128
template<bool TOP, bool BOT>
__device__ __forceinline__ void run_block(const float4* __restrict__ cmap,
                                          const int4* __restrict__ gt,
                                          const int* __restrict__ gts,
                                          float* __restrict__ ws) {
    const int tid  = threadIdx.x;
    const int slice = blockIdx.x >> 5;
    const int bis   = blockIdx.x & 31;
    const int colg  = tid & 127;             // constant across iterations
    const bool has_l = (colg != 0);
    const bool has_r = (colg != 127);
    const int lsel = has_l ? -1 : 0;         // clamped scalar-load offsets (no OOB)
    const int rsel = has_r ?  4 : 0;

    int idx = slice * GPS + bis * GPB + tid;

    float cesum = 0.f, cxy = 0.f, ed = 0.f, inter = 0.f, jsum = 0.f;
    int   isum_i = 0;

    // ---- prologue: prefetch iteration 0 ----
    float4 x; int4 c, u, d; int lm, rp;
    {
        const bool gu = TOP && (tid < 128);  // row 0: up-neighbor is zero pad
        x  = cmap[idx];
        c  = gt[idx];
        u  = gt[idx + (gu ? 0 : -128)];
        d  = gt[idx + 128];                  // it==0 rows <= 497: always safe
        lm = gts[idx * 4 + lsel];
        rp = gts[idx * 4 + rsel];
        if (gu) u = make_int4(0, 0, 0, 0);
    }

#pragma unroll
    for (int it = 0; it < ITERS; ++it) {
        // ---- prefetch next iteration while current data is consumed ----
        float4 xn; int4 cn, un, dn; int lmn, rpn;
        if (it + 1 < ITERS) {
            const int nidx = idx + BDIM;
            const bool gdn = BOT && (it + 1 == ITERS - 1) && (tid >= 128); // row 511
            xn  = cmap[nidx];
            cn  = gt[nidx];
            un  = gt[nidx - 128];            // it>=1 rows >= 2: always safe
            dn  = gt[nidx + (gdn ? 0 : 128)];
            lmn = gts[nidx * 4 + lsel];
            rpn = gts[nidx * 4 + rsel];
            if (gdn) dn = make_int4(0, 0, 0, 0);
        }

        const int lmv = has_l ? lm : 0;
        const int rpv = has_r ? rp : 0;
        const float xs[4] = {x.x, x.y, x.z, x.w};
        const int   cs[4] = {c.x, c.y, c.z, c.w};
        const int   us[4] = {u.x, u.y, u.z, u.w};
        const int   dn4[4] = {d.x, d.y, d.z, d.w};
        const int   ls[4] = {lmv, c.x, c.y, c.z};
        const int   rs[4] = {c.y, c.z, c.w, rpv};

#pragma unroll
        for (int e = 0; e < 4; ++e) {
            const float xv = xs[e];
            const float t  = __expf(-fabsf(xv));            // exp(-|x|)
            const float u1 = 1.f + t;
            const float sp = fmaxf(xv, 0.f) + __logf(u1);   // softplus(x)
            const float r  = __builtin_amdgcn_rcpf(u1);
            const float pred = (xv >= 0.f) ? r : t * r;     // sigmoid(x)
            const float yf = (float)cs[e];

            cesum += sp;
            cxy    = fmaf(xv, yf, cxy);                     // ce = cesum - cxy

            const int s = (cs[e] + us[e] + dn4[e]) + (ls[e] + rs[e]);
            if ((unsigned)(s - 1) < 4u)                     // edge <=> 0 < s < 5
                ed += fminf(sp, 100.f);

            inter   = fmaf(yf, pred, inter);
            isum_i += cs[e];
            jsum   += pred;
        }

        if (it + 1 < ITERS) {
            x = xn; c = cn; u = un; d = dn; lm = lmn; rp = rpn;
            idx += BDIM;
        }
    }

    // ---- block reduction, one write per partial, no atomics ----
    __shared__ float sm[5][4];
    const int wave = tid >> 6, lane = tid & 63;
    const float v0 = wave_reduce(cesum - cxy);
    const float v1 = wave_reduce(ed);
    const float v2 = wave_reduce(inter);
    const float v3 = wave_reduce((float)isum_i);
    const float v4 = wave_reduce(jsum);
    if (lane == 0) {
        sm[0][wave] = v0; sm[1][wave] = v1; sm[2][wave] = v2;
        sm[3][wave] = v3; sm[4][wave] = v4;
    }
    __syncthreads();
    if (tid < 5)
        ws[tid * NBLK + blockIdx.x] = sm[tid][0] + sm[tid][1] + sm[tid][2] + sm[tid][3];
}

__global__ __launch_bounds__(BDIM) void seg_main(const float4* __restrict__ cmap,
                                                 const int4* __restrict__ gt,
                                                 float* __restrict__ ws) {
    const int bis = blockIdx.x & 31;
    const int* gts = (const int*)gt;
    if (bis == 0)              run_block<true,  false>(cmap, gt, gts, ws);
    else if (bis == BPS - 1)   run_block<false, true >(cmap, gt, gts, ws);
    else                       run_block<false, false>(cmap, gt, gts, ws);
}

__global__ void seg_finish(const float* __restrict__ ws, float* __restrict__ out) {
    const int t = threadIdx.x;                   // 64 threads, one per (b,c) slice
    float ce = 0.f, ed = 0.f, inter = 0.f, is = 0.f, js = 0.f;
#pragma unroll 4
    for (int i = 0; i < BPS; ++i) {
        const int b = t * BPS + i;
        ce    += ws[0 * NBLK + b];
        ed    += ws[1 * NBLK + b];
        inter += ws[2 * NBLK + b];
        is    += ws[3 * NBLK + b];
        js    += ws[4 * NBLK + b];
    }
    const float score = (2.f * inter + SMOOTHF) / (is + js + SMOOTHF);
    float dice = (1.f - score) * (1.f / (float)Bn);   // mean over batch
    dice = wave_reduce(dice);                         // sum over C (and B slices)
    ce = wave_reduce(ce);
    ed = wave_reduce(ed);
    if (t == 0)
        out[0] = ce * (1.f / NTOT) + ed * (1.f / NTOT) + dice;
}

extern "C" void kernel_launch(void* const* d_in, const int* in_sizes, int n_in,
                              void* d_out, int out_size, void* d_ws, size_t ws_size,
                              hipStream_t stream) {
    const float4* cmap = (const float4*)d_in[0];
    const int4*   gt   = (const int4*)d_in[1];
    float* ws = (float*)d_ws;                     // 5 * 2048 floats, all rewritten
    seg_main<<<NBLK, BDIM, 0, stream>>>(cmap, gt, ws);
    seg_finish<<<1, 64, 0, stream>>>(ws, (float*)d_out);
}